// Round 5
// baseline (103.008 us; speedup 1.0000x reference)
//
#include <hip/hip_runtime.h>
#include <hip/hip_bf16.h>
#include <stdint.h>

// MahalanobisEnsembleLoss: out = sum_l w[l] * mean_n( v^T M_l v ),  v = F[l,n,:] - MEAN[l,idx[n],:]
// FP16 path: q ~= vh^T Mh vh (fp16 rel 2^-11; total err ~0.01 << 0.09 threshold).
// Single GEMM acc = Vh*Mh^T (K=512); epilogue q = sum_d vh[n,d]*acc[n,d].
// R5: 512-thr blocks (8 waves) x BN=64, LDS 64KB -> 2 blocks/CU co-resident so one
// block's HBM staging overlaps the other's K-loop; depth-2 B-prefetch ring.
#define LDIM 4
#define NDIM 16384
#define DDIM 512
#define CDIM 1000
#define BN 64
#define BK 32
#define NSTEPS (DDIM / BK)  // 16
#define WS_NEED ((size_t)LDIM * DDIM * DDIM * 2)  // 2 MiB fp16 M

typedef __attribute__((ext_vector_type(8))) _Float16 f16x8;
typedef __attribute__((ext_vector_type(4))) float f32x4;

__device__ __forceinline__ unsigned short f2h(float x) {
  union { _Float16 h; unsigned short u; } c;
  c.h = (_Float16)x;  // RNE
  return c.u;
}
__device__ __forceinline__ float h2f(unsigned short u) {
  union { unsigned short u; _Float16 h; } c;
  c.u = u;
  return (float)c.h;
}

// ---- LDS: VH [64 n][512 e] fp16, row 1024 B, 16B-granule XOR swizzle with (n&7) ----
#define LDS_BYTES 65600   // 64 KiB VH + 64 B reduction scratch
#define RED_OFF 65536
__device__ __forceinline__ int vh_addr(int n, int e) {
  return n * 1024 + (((e >> 3) ^ (n & 7)) << 4) + (e & 7) * 2;
}

// K0: convert M fp32 -> fp16 (RNE). 1024 blocks x 256 thr x 4 elems = L*D*D.
extern "C" __global__ void mel_mconv(const float* __restrict__ IC,
                                     unsigned short* __restrict__ MH) {
  size_t i = ((size_t)blockIdx.x * 256 + threadIdx.x) * 4;
  float4 v = *(const float4*)(IC + i);
  *(ushort4*)(MH + i) = make_ushort4(f2h(v.x), f2h(v.y), f2h(v.z), f2h(v.w));
}

// Main: 512 thr = 8 waves; wave owns 64 d-cols (4 B-frags) x 64 n-rows (4 A-frags).
// V persists in LDS; B streams from XCD-local L2 with depth-2 register ring.
// Zero barriers in the K-loop. Grid 1024: xcd=bid&7 -> l=xcd>>1 (Mh L2-resident).
extern "C" __global__ __launch_bounds__(512, 2)
void mel_main(const float* __restrict__ F, const float* __restrict__ MEAN,
              const float* __restrict__ W, const int* __restrict__ IDX,
              const unsigned short* __restrict__ MH,
              float* __restrict__ OUT) {
  extern __shared__ __align__(16) char lds[];
  const int t = threadIdx.x;
  const int lane = t & 63;
  const int w = t >> 6;          // 8 waves
  const int bid = blockIdx.x;
  const int xcd = bid & 7;
  const int l = xcd >> 1;
  const int bx = ((bid >> 3) << 1) + (xcd & 1);  // 0..255 within l
  const int n0 = bx * BN;
  const int col0 = w * 64;       // wave's d-column base (4 frags)
  const int lrow = lane & 15;
  const int lke = (lane >> 4) << 3;  // k-offset 0,8,16,24

  // ---- stage V: gather mean row, subtract, fp16-convert into LDS
  {
    const int sn = t >> 3;          // 64 rows, 8 threads/row
    const int cls = IDX[n0 + sn];
    const float4* fr = (const float4*)(F + ((size_t)l * NDIM + n0 + sn) * DDIM);
    const float4* mr = (const float4*)(MEAN + ((size_t)l * CDIM + cls) * DDIM);
    float4 fv[16], mv[16];
#pragma unroll
    for (int j = 0; j < 16; ++j) fv[j] = fr[(t & 7) + 8 * j];
#pragma unroll
    for (int j = 0; j < 16; ++j) mv[j] = mr[(t & 7) + 8 * j];
#pragma unroll
    for (int j = 0; j < 16; ++j) {
      const int e = ((t & 7) + 8 * j) * 4;
      *(ushort4*)(lds + vh_addr(sn, e)) =
          make_ushort4(f2h(fv[j].x - mv[j].x), f2h(fv[j].y - mv[j].y),
                       f2h(fv[j].z - mv[j].z), f2h(fv[j].w - mv[j].w));
    }
  }
  __syncthreads();  // only barrier before epilogue

  const unsigned short* mh_l = MH + (size_t)l * DDIM * DDIM;

  f32x4 acc[4][4];  // [n-frag][d-frag]
#pragma unroll
  for (int i = 0; i < 4; ++i)
#pragma unroll
    for (int j = 0; j < 4; ++j) acc[i][j] = {0.f, 0.f, 0.f, 0.f};

  // ---- K-loop: A from LDS, B from L2, depth-2 named-register ring. No barriers.
  const unsigned short* bp0 = mh_l + (size_t)(col0 + lrow) * DDIM + lke;
  const unsigned short* bp1 = bp0 + 16 * DDIM;
  const unsigned short* bp2 = bp0 + 32 * DDIM;
  const unsigned short* bp3 = bp0 + 48 * DDIM;
  f16x8 be0 = *(const f16x8*)(bp0);
  f16x8 be1 = *(const f16x8*)(bp1);
  f16x8 be2 = *(const f16x8*)(bp2);
  f16x8 be3 = *(const f16x8*)(bp3);
  f16x8 bo0 = *(const f16x8*)(bp0 + BK);
  f16x8 bo1 = *(const f16x8*)(bp1 + BK);
  f16x8 bo2 = *(const f16x8*)(bp2 + BK);
  f16x8 bo3 = *(const f16x8*)(bp3 + BK);
#pragma unroll
  for (int p = 0; p < NSTEPS / 2; ++p) {
    const int s0 = 2 * p, s1 = 2 * p + 1;
    // even step
    {
      f16x8 ne0, ne1, ne2, ne3;
      if (s0 + 2 < NSTEPS) {
        const int o = (s0 + 2) * BK;
        ne0 = *(const f16x8*)(bp0 + o);
        ne1 = *(const f16x8*)(bp1 + o);
        ne2 = *(const f16x8*)(bp2 + o);
        ne3 = *(const f16x8*)(bp3 + o);
      }
      const int e0 = s0 * BK + lke;
      f16x8 a0 = *(const f16x8*)(lds + vh_addr(lrow, e0));
      f16x8 a1 = *(const f16x8*)(lds + vh_addr(16 + lrow, e0));
      f16x8 a2 = *(const f16x8*)(lds + vh_addr(32 + lrow, e0));
      f16x8 a3 = *(const f16x8*)(lds + vh_addr(48 + lrow, e0));
#pragma unroll
      for (int nf = 0; nf < 4; ++nf) {
        f16x8 a = nf == 0 ? a0 : nf == 1 ? a1 : nf == 2 ? a2 : a3;
        acc[nf][0] = __builtin_amdgcn_mfma_f32_16x16x32_f16(a, be0, acc[nf][0], 0, 0, 0);
        acc[nf][1] = __builtin_amdgcn_mfma_f32_16x16x32_f16(a, be1, acc[nf][1], 0, 0, 0);
        acc[nf][2] = __builtin_amdgcn_mfma_f32_16x16x32_f16(a, be2, acc[nf][2], 0, 0, 0);
        acc[nf][3] = __builtin_amdgcn_mfma_f32_16x16x32_f16(a, be3, acc[nf][3], 0, 0, 0);
      }
      if (s0 + 2 < NSTEPS) { be0 = ne0; be1 = ne1; be2 = ne2; be3 = ne3; }
    }
    // odd step
    {
      f16x8 no0, no1, no2, no3;
      if (s1 + 2 < NSTEPS) {
        const int o = (s1 + 2) * BK;
        no0 = *(const f16x8*)(bp0 + o);
        no1 = *(const f16x8*)(bp1 + o);
        no2 = *(const f16x8*)(bp2 + o);
        no3 = *(const f16x8*)(bp3 + o);
      }
      const int e0 = s1 * BK + lke;
      f16x8 a0 = *(const f16x8*)(lds + vh_addr(lrow, e0));
      f16x8 a1 = *(const f16x8*)(lds + vh_addr(16 + lrow, e0));
      f16x8 a2 = *(const f16x8*)(lds + vh_addr(32 + lrow, e0));
      f16x8 a3 = *(const f16x8*)(lds + vh_addr(48 + lrow, e0));
#pragma unroll
      for (int nf = 0; nf < 4; ++nf) {
        f16x8 a = nf == 0 ? a0 : nf == 1 ? a1 : nf == 2 ? a2 : a3;
        acc[nf][0] = __builtin_amdgcn_mfma_f32_16x16x32_f16(a, bo0, acc[nf][0], 0, 0, 0);
        acc[nf][1] = __builtin_amdgcn_mfma_f32_16x16x32_f16(a, bo1, acc[nf][1], 0, 0, 0);
        acc[nf][2] = __builtin_amdgcn_mfma_f32_16x16x32_f16(a, bo2, acc[nf][2], 0, 0, 0);
        acc[nf][3] = __builtin_amdgcn_mfma_f32_16x16x32_f16(a, bo3, acc[nf][3], 0, 0, 0);
      }
      if (s1 + 2 < NSTEPS) { bo0 = no0; bo1 = no1; bo2 = no2; bo3 = no3; }
    }
  }

  // ---- epilogue: q = sum vh[n,dcol] * acc. C-frag: col=lane&15, row=(lane>>4)*4+r
  float tsum = 0.f;
#pragma unroll
  for (int nf = 0; nf < 4; ++nf) {
#pragma unroll
    for (int df = 0; df < 4; ++df) {
      const int dcol = col0 + df * 16 + lrow;
      const int nb = nf * 16 + ((lane >> 4) << 2);
      f32x4 c = acc[nf][df];
#pragma unroll
      for (int r = 0; r < 4; ++r) {
        unsigned short hv = *(const unsigned short*)(lds + vh_addr(nb + r, dcol));
        tsum += h2f(hv) * c[r];
      }
    }
  }
#pragma unroll
  for (int off = 32; off > 0; off >>= 1) tsum += __shfl_down(tsum, off);
  __syncthreads();
  float* red = (float*)(lds + RED_OFF);
  if (lane == 0) red[w] = tsum;
  __syncthreads();
  if (t == 0) {
    float ssum = 0.f;
#pragma unroll
    for (int i = 0; i < 8; ++i) ssum += red[i];
    atomicAdd(OUT, ssum * (W[l] / (float)NDIM));
  }
}

// Correct-but-slow fp32 fallback (only if ws_size < WS_NEED).
extern "C" __global__ void mel_fallback(const float* __restrict__ F,
                                        const float* __restrict__ MEAN,
                                        const float* __restrict__ IC,
                                        const float* __restrict__ W,
                                        const int* __restrict__ IDX,
                                        float* __restrict__ OUT) {
  __shared__ float v[8][DDIM];
  __shared__ float red[256];
  const int t = threadIdx.x;
  const int l = blockIdx.y;
  const int n0 = blockIdx.x * 8;
  for (int i = t; i < 8 * DDIM; i += 256) {
    int n = i >> 9, e = i & 511;
    int c = IDX[n0 + n];
    v[n][e] = F[((size_t)l * NDIM + n0 + n) * DDIM + e] -
              MEAN[((size_t)l * CDIM + c) * DDIM + e];
  }
  __syncthreads();
  const float* icl = IC + ((size_t)l << 18);
  float part = 0.f;
  for (int rep = 0; rep < 2; ++rep) {
    int d = t + rep * 256;
    float s[8];
#pragma unroll
    for (int j = 0; j < 8; ++j) s[j] = 0.f;
    for (int e = 0; e < DDIM; ++e) {
      float m = icl[(size_t)d * DDIM + e];
#pragma unroll
      for (int j = 0; j < 8; ++j) s[j] += m * v[j][e];
    }
#pragma unroll
    for (int j = 0; j < 8; ++j) part += v[j][d] * s[j];
  }
  red[t] = part;
  __syncthreads();
  for (int o = 128; o > 0; o >>= 1) {
    if (t < o) red[t] += red[t + o];
    __syncthreads();
  }
  if (t == 0) atomicAdd(OUT, red[0] * (W[l] / (float)NDIM));
}

extern "C" void kernel_launch(void* const* d_in, const int* in_sizes, int n_in,
                              void* d_out, int out_size, void* d_ws, size_t ws_size,
                              hipStream_t stream) {
  const float* F = (const float*)d_in[0];
  const float* MEAN = (const float*)d_in[1];
  const float* IC = (const float*)d_in[2];
  const float* W = (const float*)d_in[3];
  const int* IDX = (const int*)d_in[4];
  float* OUT = (float*)d_out;

  hipMemsetAsync(d_out, 0, sizeof(float) * (size_t)out_size, stream);

  if (ws_size >= WS_NEED) {
    unsigned short* MH = (unsigned short*)d_ws;
    mel_mconv<<<dim3(1024), dim3(256), 0, stream>>>(IC, MH);
    (void)hipFuncSetAttribute(reinterpret_cast<const void*>(mel_main),
                              hipFuncAttributeMaxDynamicSharedMemorySize, LDS_BYTES);
    mel_main<<<dim3(1024), dim3(512), LDS_BYTES, stream>>>(
        F, MEAN, W, IDX, MH, OUT);
  } else {
    mel_fallback<<<dim3(NDIM / 8, LDIM), dim3(256), 0, stream>>>(F, MEAN, IC, W, IDX, OUT);
  }
}

// Round 6
// 90.781 us; speedup vs baseline: 1.1347x; 1.1347x over previous
//
#include <hip/hip_runtime.h>
#include <hip/hip_bf16.h>
#include <stdint.h>

// MahalanobisEnsembleLoss: out = sum_l w[l] * mean_n( v^T M_l v ),  v = F[l,n,:] - MEAN[l,idx[n],:]
// FP16 path: q ~= vh^T Mh vh (fp16 rel 2^-11; total err ~0.01 << 0.09 threshold).
// R6: flash-style fused pipeline. V-tile persists in LDS as 8 chunks of BK=64 e-cols;
// step s: issue chunk s+1 global loads (regs) || MFMA chunk s (B from L2 reg-ring) ||
// convert+ds_write chunk s+1 || barrier. Stage latency hides under the HBM stream.
#define LDIM 4
#define NDIM 16384
#define DDIM 512
#define CDIM 1000
#define BN 64
#define BK 64
#define NSTEPS (DDIM / BK)  // 8
#define WS_NEED ((size_t)LDIM * DDIM * DDIM * 2)  // 2 MiB fp16 M

typedef __attribute__((ext_vector_type(8))) _Float16 f16x8;
typedef __attribute__((ext_vector_type(4))) float f32x4;

__device__ __forceinline__ unsigned short f2h(float x) {
  union { _Float16 h; unsigned short u; } c;
  c.h = (_Float16)x;  // RNE
  return c.u;
}
__device__ __forceinline__ float h2f(unsigned short u) {
  union { unsigned short u; _Float16 h; } c;
  c.u = u;
  return (float)c.h;
}

// ---- LDS: VH [64 n][512 e] fp16, row 1024 B, 16B-granule XOR swizzle with (n&7) ----
#define LDS_BYTES 65600   // 64 KiB VH + 64 B reduction scratch
#define RED_OFF 65536
__device__ __forceinline__ int vh_addr(int n, int e) {
  return n * 1024 + (((e >> 3) ^ (n & 7)) << 4) + (e & 7) * 2;
}

// K0: convert M fp32 -> fp16 (RNE). 1024 blocks x 256 thr x 4 elems = L*D*D.
extern "C" __global__ void mel_mconv(const float* __restrict__ IC,
                                     unsigned short* __restrict__ MH) {
  size_t i = ((size_t)blockIdx.x * 256 + threadIdx.x) * 4;
  float4 v = *(const float4*)(IC + i);
  *(ushort4*)(MH + i) = make_ushort4(f2h(v.x), f2h(v.y), f2h(v.z), f2h(v.w));
}

// Main: 1024 thr = 16 waves; wave owns 32 d-cols (2 B-frags) x 64 n-rows (4 A-frags),
// acc[4][2] = 32 regs. Grid 1024 tiles; xcd=bid&7 -> l=xcd>>1 (Mh XCD-L2-resident).
extern "C" __global__ __launch_bounds__(1024, 3)
void mel_main(const float* __restrict__ F, const float* __restrict__ MEAN,
              const float* __restrict__ W, const int* __restrict__ IDX,
              const unsigned short* __restrict__ MH,
              float* __restrict__ OUT) {
  extern __shared__ __align__(16) char lds[];
  const int t = threadIdx.x;
  const int lane = t & 63;
  const int w = t >> 6;          // 16 waves
  const int bid = blockIdx.x;
  const int xcd = bid & 7;
  const int l = xcd >> 1;
  const int bx = ((bid >> 3) << 1) + (xcd & 1);  // 0..255 within l
  const int n0 = bx * BN;
  const int col0 = w * 32;       // wave's d-column base (2 frags)
  const int lrow = lane & 15;
  const int lke = (lane >> 4) << 3;  // k-offset 0,8,16,24

  // staging coords: thread -> (row = t>>4, e-quad (t&15)*4 within 64-col chunk)
  const int srow = t >> 4;
  const int se4 = (t & 15) << 2;
  const int cls = IDX[n0 + srow];
  const float* fr = F + ((size_t)l * NDIM + n0 + srow) * DDIM;
  const float* mr = MEAN + ((size_t)l * CDIM + cls) * DDIM;

  // B-ring base: wave's d-rows of Mh, k at lke
  const unsigned short* bbase =
      MH + (size_t)l * DDIM * DDIM + (size_t)(col0 + lrow) * DDIM + lke;

  // ---- prologue: chunk 0 stage + B-ring fill for step 0
  float4 pf = *(const float4*)(fr + se4);
  float4 pm = *(const float4*)(mr + se4);
  f16x8 bc00 = *(const f16x8*)(bbase);              // kh=0, df=0
  f16x8 bc01 = *(const f16x8*)(bbase + 16 * DDIM);  // kh=0, df=1
  f16x8 bc10 = *(const f16x8*)(bbase + 32);         // kh=1, df=0
  f16x8 bc11 = *(const f16x8*)(bbase + 32 + 16 * DDIM);
  *(ushort4*)(lds + vh_addr(srow, se4)) =
      make_ushort4(f2h(pf.x - pm.x), f2h(pf.y - pm.y),
                   f2h(pf.z - pm.z), f2h(pf.w - pm.w));
  __syncthreads();

  f32x4 acc[4][2];  // [n-frag][d-frag]
#pragma unroll
  for (int i = 0; i < 4; ++i)
#pragma unroll
    for (int j = 0; j < 2; ++j) acc[i][j] = {0.f, 0.f, 0.f, 0.f};

  // ---- pipelined K-loop: 8 steps of BK=64
#pragma unroll
  for (int s = 0; s < NSTEPS; ++s) {
    // (a) issue next chunk's F/MEAN loads (registers; consumed after MFMAs)
    float4 nf4, nm4;
    if (s < NSTEPS - 1) {
      nf4 = *(const float4*)(fr + (s + 1) * BK + se4);
      nm4 = *(const float4*)(mr + (s + 1) * BK + se4);
    }
    // (b) issue next step's B-frags (L2 hits)
    f16x8 bn00, bn01, bn10, bn11;
    if (s < NSTEPS - 1) {
      const unsigned short* nb = bbase + (s + 1) * BK;
      bn00 = *(const f16x8*)(nb);
      bn01 = *(const f16x8*)(nb + 16 * DDIM);
      bn10 = *(const f16x8*)(nb + 32);
      bn11 = *(const f16x8*)(nb + 32 + 16 * DDIM);
    }
    // (c) MFMAs on chunk s: kh=0 then kh=1
    {
      const int e0 = s * BK + lke;
      f16x8 a0 = *(const f16x8*)(lds + vh_addr(lrow, e0));
      f16x8 a1 = *(const f16x8*)(lds + vh_addr(16 + lrow, e0));
      f16x8 a2 = *(const f16x8*)(lds + vh_addr(32 + lrow, e0));
      f16x8 a3 = *(const f16x8*)(lds + vh_addr(48 + lrow, e0));
      acc[0][0] = __builtin_amdgcn_mfma_f32_16x16x32_f16(a0, bc00, acc[0][0], 0, 0, 0);
      acc[1][0] = __builtin_amdgcn_mfma_f32_16x16x32_f16(a1, bc00, acc[1][0], 0, 0, 0);
      acc[2][0] = __builtin_amdgcn_mfma_f32_16x16x32_f16(a2, bc00, acc[2][0], 0, 0, 0);
      acc[3][0] = __builtin_amdgcn_mfma_f32_16x16x32_f16(a3, bc00, acc[3][0], 0, 0, 0);
      acc[0][1] = __builtin_amdgcn_mfma_f32_16x16x32_f16(a0, bc01, acc[0][1], 0, 0, 0);
      acc[1][1] = __builtin_amdgcn_mfma_f32_16x16x32_f16(a1, bc01, acc[1][1], 0, 0, 0);
      acc[2][1] = __builtin_amdgcn_mfma_f32_16x16x32_f16(a2, bc01, acc[2][1], 0, 0, 0);
      acc[3][1] = __builtin_amdgcn_mfma_f32_16x16x32_f16(a3, bc01, acc[3][1], 0, 0, 0);
      const int e1 = e0 + 32;
      f16x8 c0 = *(const f16x8*)(lds + vh_addr(lrow, e1));
      f16x8 c1 = *(const f16x8*)(lds + vh_addr(16 + lrow, e1));
      f16x8 c2 = *(const f16x8*)(lds + vh_addr(32 + lrow, e1));
      f16x8 c3 = *(const f16x8*)(lds + vh_addr(48 + lrow, e1));
      acc[0][0] = __builtin_amdgcn_mfma_f32_16x16x32_f16(c0, bc10, acc[0][0], 0, 0, 0);
      acc[1][0] = __builtin_amdgcn_mfma_f32_16x16x32_f16(c1, bc10, acc[1][0], 0, 0, 0);
      acc[2][0] = __builtin_amdgcn_mfma_f32_16x16x32_f16(c2, bc10, acc[2][0], 0, 0, 0);
      acc[3][0] = __builtin_amdgcn_mfma_f32_16x16x32_f16(c3, bc10, acc[3][0], 0, 0, 0);
      acc[0][1] = __builtin_amdgcn_mfma_f32_16x16x32_f16(c0, bc11, acc[0][1], 0, 0, 0);
      acc[1][1] = __builtin_amdgcn_mfma_f32_16x16x32_f16(c1, bc11, acc[1][1], 0, 0, 0);
      acc[2][1] = __builtin_amdgcn_mfma_f32_16x16x32_f16(c2, bc11, acc[2][1], 0, 0, 0);
      acc[3][1] = __builtin_amdgcn_mfma_f32_16x16x32_f16(c3, bc11, acc[3][1], 0, 0, 0);
    }
    // (d) convert + ds_write chunk s+1 (vmcnt wait lands here, after MFMAs)
    if (s < NSTEPS - 1) {
      *(ushort4*)(lds + vh_addr(srow, (s + 1) * BK + se4)) =
          make_ushort4(f2h(nf4.x - nm4.x), f2h(nf4.y - nm4.y),
                       f2h(nf4.z - nm4.z), f2h(nf4.w - nm4.w));
      bc00 = bn00; bc01 = bn01; bc10 = bn10; bc11 = bn11;
    }
    __syncthreads();
  }

  // ---- epilogue: q = sum vh[n,dcol] * acc. C-frag: col=lane&15, row=(lane>>4)*4+r
  float tsum = 0.f;
#pragma unroll
  for (int nf = 0; nf < 4; ++nf) {
#pragma unroll
    for (int df = 0; df < 2; ++df) {
      const int dcol = col0 + df * 16 + lrow;
      const int nb = nf * 16 + ((lane >> 4) << 2);
      f32x4 c = acc[nf][df];
#pragma unroll
      for (int r = 0; r < 4; ++r) {
        unsigned short hv = *(const unsigned short*)(lds + vh_addr(nb + r, dcol));
        tsum += h2f(hv) * c[r];
      }
    }
  }
#pragma unroll
  for (int off = 32; off > 0; off >>= 1) tsum += __shfl_down(tsum, off);
  __syncthreads();
  float* red = (float*)(lds + RED_OFF);
  if (lane == 0) red[w] = tsum;
  __syncthreads();
  if (t == 0) {
    float ssum = 0.f;
#pragma unroll
    for (int i = 0; i < 16; ++i) ssum += red[i];
    atomicAdd(OUT, ssum * (W[l] / (float)NDIM));
  }
}

// Correct-but-slow fp32 fallback (only if ws_size < WS_NEED).
extern "C" __global__ void mel_fallback(const float* __restrict__ F,
                                        const float* __restrict__ MEAN,
                                        const float* __restrict__ IC,
                                        const float* __restrict__ W,
                                        const int* __restrict__ IDX,
                                        float* __restrict__ OUT) {
  __shared__ float v[8][DDIM];
  __shared__ float red[256];
  const int t = threadIdx.x;
  const int l = blockIdx.y;
  const int n0 = blockIdx.x * 8;
  for (int i = t; i < 8 * DDIM; i += 256) {
    int n = i >> 9, e = i & 511;
    int c = IDX[n0 + n];
    v[n][e] = F[((size_t)l * NDIM + n0 + n) * DDIM + e] -
              MEAN[((size_t)l * CDIM + c) * DDIM + e];
  }
  __syncthreads();
  const float* icl = IC + ((size_t)l << 18);
  float part = 0.f;
  for (int rep = 0; rep < 2; ++rep) {
    int d = t + rep * 256;
    float s[8];
#pragma unroll
    for (int j = 0; j < 8; ++j) s[j] = 0.f;
    for (int e = 0; e < DDIM; ++e) {
      float m = icl[(size_t)d * DDIM + e];
#pragma unroll
      for (int j = 0; j < 8; ++j) s[j] += m * v[j][e];
    }
#pragma unroll
    for (int j = 0; j < 8; ++j) part += v[j][d] * s[j];
  }
  red[t] = part;
  __syncthreads();
  for (int o = 128; o > 0; o >>= 1) {
    if (t < o) red[t] += red[t + o];
    __syncthreads();
  }
  if (t == 0) atomicAdd(OUT, red[0] * (W[l] / (float)NDIM));
}

extern "C" void kernel_launch(void* const* d_in, const int* in_sizes, int n_in,
                              void* d_out, int out_size, void* d_ws, size_t ws_size,
                              hipStream_t stream) {
  const float* F = (const float*)d_in[0];
  const float* MEAN = (const float*)d_in[1];
  const float* IC = (const float*)d_in[2];
  const float* W = (const float*)d_in[3];
  const int* IDX = (const int*)d_in[4];
  float* OUT = (float*)d_out;

  hipMemsetAsync(d_out, 0, sizeof(float) * (size_t)out_size, stream);

  if (ws_size >= WS_NEED) {
    unsigned short* MH = (unsigned short*)d_ws;
    mel_mconv<<<dim3(1024), dim3(256), 0, stream>>>(IC, MH);
    (void)hipFuncSetAttribute(reinterpret_cast<const void*>(mel_main),
                              hipFuncAttributeMaxDynamicSharedMemorySize, LDS_BYTES);
    mel_main<<<dim3(1024), dim3(1024), LDS_BYTES, stream>>>(
        F, MEAN, W, IDX, MH, OUT);
  } else {
    mel_fallback<<<dim3(NDIM / 8, LDIM), dim3(256), 0, stream>>>(F, MEAN, IC, W, IDX, OUT);
  }
}